// Round 3
// baseline (623.732 us; speedup 1.0000x reference)
//
#include <hip/hip_runtime.h>
#include <hip/hip_bf16.h>

typedef __bf16 bf16x8 __attribute__((ext_vector_type(8)));
typedef float f32x4 __attribute__((ext_vector_type(4)));

#define TOKENS 8192
#define D_IN   4096
#define D_OUT  4096

// fp32 -> bf16 bits, round-to-nearest-even
static __device__ __forceinline__ unsigned short f2bf(float f) {
  union { float f; unsigned int u; } v; v.f = f;
  unsigned int r = v.u + 0x7FFFu + ((v.u >> 16) & 1u);
  return (unsigned short)(r >> 16);
}

// ---------------------------------------------------------------------------
// Kernel 1: ABt[o][f*64+k] = sum_r tanh(As[f,o,r]) * Bs[f,r,k]
// ---------------------------------------------------------------------------
__global__ void ab_kernel(const float* __restrict__ As,
                          const float* __restrict__ Bs,
                          float* __restrict__ ABt) {
  __shared__ float tA[4][64];
  __shared__ float sB[64][64];
  const int t = threadIdx.x;
  const int f = blockIdx.x >> 10;
  const int o0 = (blockIdx.x & 1023) * 4;
  const int ol = t >> 6;
  const int k  = t & 63;
  tA[ol][k] = tanhf(As[((size_t)f * 4096 + o0 + ol) * 64 + k]);
#pragma unroll
  for (int j = 0; j < 16; ++j) {
    int e = t + 256 * j;
    sB[e >> 6][e & 63] = Bs[f * 4096 + e];
  }
  __syncthreads();
  float acc = 0.f;
#pragma unroll
  for (int r = 0; r < 64; ++r) acc += tA[ol][r] * sB[r][k];
  ABt[(size_t)(o0 + ol) * 128 + f * 64 + k] = acc;
}

// ---------------------------------------------------------------------------
// Kernel 2: Weff[o][i] = bf16( W[o][i] + sum_fk ABt[o][fk] * Cs[fk][i] )
// ---------------------------------------------------------------------------
__global__ void weff_kernel(const float* __restrict__ W,
                            const float* __restrict__ ABt,
                            const float* __restrict__ Cs,
                            unsigned short* __restrict__ Weff) {
  __shared__ float sA[64][129];
  __shared__ float sB[32][64];
  const int t = threadIdx.x;
  const int i0 = blockIdx.x * 64;
  const int o0 = blockIdx.y * 64;
#pragma unroll
  for (int j = 0; j < 32; ++j) {
    int e = t + 256 * j;
    sA[e >> 7][e & 127] = ABt[(size_t)(o0 + (e >> 7)) * 128 + (e & 127)];
  }
  const int tx = t & 15, ty = t >> 4;
  float acc[4][4] = {};
  for (int kc = 0; kc < 128; kc += 32) {
    __syncthreads();
#pragma unroll
    for (int j = 0; j < 8; ++j) {
      int e = t + 256 * j;
      sB[e >> 6][e & 63] = Cs[(size_t)(kc + (e >> 6)) * D_IN + i0 + (e & 63)];
    }
    __syncthreads();
#pragma unroll
    for (int k = 0; k < 32; ++k) {
      float4 b = *(const float4*)&sB[k][tx * 4];
#pragma unroll
      for (int r = 0; r < 4; ++r) {
        float a = sA[ty * 4 + r][kc + k];
        acc[r][0] += a * b.x;
        acc[r][1] += a * b.y;
        acc[r][2] += a * b.z;
        acc[r][3] += a * b.w;
      }
    }
  }
#pragma unroll
  for (int r = 0; r < 4; ++r) {
    const int o = o0 + ty * 4 + r;
    const float4 w = *(const float4*)&W[(size_t)o * D_IN + i0 + tx * 4];
    union { unsigned short h[4]; uint2 u; } p;
    p.h[0] = f2bf(w.x + acc[r][0]);
    p.h[1] = f2bf(w.y + acc[r][1]);
    p.h[2] = f2bf(w.z + acc[r][2]);
    p.h[3] = f2bf(w.w + acc[r][3]);
    *(uint2*)(Weff + (size_t)o * D_IN + i0 + tx * 4) = p.u;
  }
}

// ---------------------------------------------------------------------------
// Kernel 3: cast x (fp32) -> bf16, 8 elems/thread
// ---------------------------------------------------------------------------
__global__ void cast_kernel(const float* __restrict__ x,
                            unsigned short* __restrict__ xb) {
  size_t i = ((size_t)blockIdx.x * 256 + threadIdx.x) * 8;
  float4 a = *(const float4*)(x + i);
  float4 b = *(const float4*)(x + i + 4);
  union { unsigned short h[8]; uint4 u; } p;
  p.h[0] = f2bf(a.x); p.h[1] = f2bf(a.y);
  p.h[2] = f2bf(a.z); p.h[3] = f2bf(a.w);
  p.h[4] = f2bf(b.x); p.h[5] = f2bf(b.y);
  p.h[6] = f2bf(b.z); p.h[7] = f2bf(b.w);
  *(uint4*)(xb + i) = p.u;
}

// ---------------------------------------------------------------------------
// Kernel 4: main GEMM  C[m][n] = sum_k A[m][k]*B[n][k] + bias[n]
//
// 256x256 tile, BK=64, 8 waves (2M x 4N), 8-phase counted-vmcnt schedule.
// Round-3 change (R2 post-mortem: B-fragment burst of 8 ds_reads consumed
// in-phase at p0/p4 was the exposed stall; ~1150 cyc of CU LDS-pipe time
// dumped at once, QUAD blocked on it):
//   - B fragments double-buffered in regs (pingB/pongB, +32 VGPR).
//   - ALL frag reads spread evenly: 6 ds_read_b128/phase/wave (4 A + 2 B),
//     each issued a full phase (~900 cyc) before its consumer.
//   - Staging re-pipelined, 4 counted publishes/body (FIFO-verified):
//     entering each body: 4 loads in flight (next tile's A).
//     end-p2 vmcnt(4): A(T+1) ready.   end-p3 vmcnt(2): B(T+2) ready.
//     end-p6 vmcnt(4): A(T+2) ready.   end-p7 vmcnt(4): B(T+3) ready.
//   - Stage issue points (>=1 barrier after region's last frag-read):
//     p0/p1: B(T+2)->buf0 (buf0.B last read prev-p7)
//     p3/p4: A(T+2)->buf0 (buf0.A last read p2)
//     p4/p5: B(T+3)->buf1 (buf1.B last read p3)
//     p7:    A(T+3)->buf1 both halves (buf1.A last read p6)
// ---------------------------------------------------------------------------

#define FENCE()   asm volatile("" ::: "memory")
#define BARRIER() do { FENCE(); __builtin_amdgcn_s_barrier(); FENCE(); } while (0)
#define WAITVM(n)  asm volatile("s_waitcnt vmcnt(" #n ")" ::: "memory")
#define SCHEDB()   __builtin_amdgcn_sched_barrier(0)
#define PRIO1      __builtin_amdgcn_s_setprio(1)
#define PRIO0      __builtin_amdgcn_s_setprio(0)

#define GLOAD(gptr, lptr)                                                     \
  __builtin_amdgcn_global_load_lds(                                           \
      (const __attribute__((address_space(1))) void*)(gptr),                  \
      (__attribute__((address_space(3))) void*)(lptr), 16, 0, 0)

// one operand-half = 128 rows x 64 k = 16 KB = 2 loads/thread (512 thr x 16B)
#define STAGE_A(buf, h, kt) do {                                              \
    GLOAD(ag + (size_t)((h) * 128) * K + (kt),                                \
          lA + (buf) * 16384 + (h) * 8192);                                   \
    GLOAD(ag + (size_t)((h) * 128 + 64) * K + (kt),                           \
          lA + (buf) * 16384 + (h) * 8192 + 4096);                            \
  } while (0)
#define STAGE_B(buf, h, kt) do {                                              \
    GLOAD(bg + (size_t)((h) * 128) * K + (kt),                                \
          lB + (buf) * 16384 + (h) * 8192);                                   \
    GLOAD(bg + (size_t)((h) * 128 + 64) * K + (kt),                           \
          lB + (buf) * 16384 + (h) * 8192 + 4096);                            \
  } while (0)

#define LDA(buf, mi, ks) \
  (*(const bf16x8*)(rA + (buf) * 16384 + (mi) * 1024 + ((ks) ? ch1 : ch0)))
#define LDB(buf, ni, ks) \
  (*(const bf16x8*)(rB + (buf) * 16384 + (ni) * 1024 + ((ks) ? ch1 : ch0)))

// A frag set: R0 = mi-even ks0, R1 = mi-even ks1, R2 = mi-odd ks0, R3 = odd ks1
#define READ_A(R0, R1, R2, R3, buf, mi0) do {                                 \
    R0 = LDA(buf, (mi0), 0);                                                  \
    R2 = LDA(buf, (mi0) + 1, 0);                                              \
    R1 = LDA(buf, (mi0), 1);                                                  \
    R3 = LDA(buf, (mi0) + 1, 1);                                              \
  } while (0)
// one ni-column pair of B (2 reads) into set Bp (names Bp<ni><ks>)
#define READ_B1(Bp, buf, ni) do {                                             \
    Bp##ni##0 = LDB(buf, ni, 0);                                              \
    Bp##ni##1 = LDB(buf, ni, 1);                                              \
  } while (0)

#define MFMA1(d, a, b) \
  (d) = __builtin_amdgcn_mfma_f32_16x16x32_bf16((a), (b), (d), 0, 0, 0)

#define PBSET pb00, pb10, pb20, pb30, pb01, pb11, pb21, pb31
#define QBSET qb00, qb10, qb20, qb30, qb01, qb11, qb21, qb31
#define QUAD(...) QUAD_I(__VA_ARGS__)
// 16 MFMAs: mi {2q,2q+1} x ni 0..3 x ks 0..1 (ks0 half first)
#define QUAD_I(q, A0, A1, A2, A3, B00, B10, B20, B30, B01, B11, B21, B31)     \
    MFMA1(acc[2*(q)  ][0], A0, B00);                                          \
    MFMA1(acc[2*(q)+1][0], A2, B00);                                          \
    MFMA1(acc[2*(q)  ][1], A0, B10);                                          \
    MFMA1(acc[2*(q)+1][1], A2, B10);                                          \
    MFMA1(acc[2*(q)  ][2], A0, B20);                                          \
    MFMA1(acc[2*(q)+1][2], A2, B20);                                          \
    MFMA1(acc[2*(q)  ][3], A0, B30);                                          \
    MFMA1(acc[2*(q)+1][3], A2, B30);                                          \
    MFMA1(acc[2*(q)  ][0], A1, B01);                                          \
    MFMA1(acc[2*(q)+1][0], A3, B01);                                          \
    MFMA1(acc[2*(q)  ][1], A1, B11);                                          \
    MFMA1(acc[2*(q)+1][1], A3, B11);                                          \
    MFMA1(acc[2*(q)  ][2], A1, B21);                                          \
    MFMA1(acc[2*(q)+1][2], A3, B21);                                          \
    MFMA1(acc[2*(q)  ][3], A1, B31);                                          \
    MFMA1(acc[2*(q)+1][3], A3, B31);

// S2/S3: compile-time flags, tiles T+2 / T+3 exist (tail peel).
// Consume: p0-p3 = QUADs of T (pingB, pa/qa alternating from prev-p7's A01);
//          p4-p7 = QUADs of T+1 (pongB). Reads always one phase ahead.
#define GEMM_BODY(S2, S3, kt)                                                 \
  {                                                                           \
    { /* p0: Q0(T). reads A23(T), B(T+1)ni0. stage B(T+2)h0 */                \
      READ_A(qa0, qa1, qa2, qa3, 0, 2);                                       \
      READ_B1(qb, 1, 0);                                                      \
      if (S2) STAGE_B(0, 0, (kt) + 128);                                      \
      BARRIER(); SCHEDB();                                                    \
      PRIO1; QUAD(0, pa0, pa1, pa2, pa3, PBSET); PRIO0; SCHEDB();             \
      BARRIER();                                                              \
    }                                                                         \
    { /* p1: Q1(T). reads A45(T), B(T+1)ni1. stage B(T+2)h1 */                \
      READ_A(pa0, pa1, pa2, pa3, 0, 4);                                       \
      READ_B1(qb, 1, 1);                                                      \
      if (S2) STAGE_B(0, 1, (kt) + 128);                                      \
      BARRIER(); SCHEDB();                                                    \
      PRIO1; QUAD(1, qa0, qa1, qa2, qa3, PBSET); PRIO0; SCHEDB();             \
      BARRIER();                                                              \
    }                                                                         \
    { /* p2: Q2(T). reads A67(T), B(T+1)ni2. publish A(T+1) */                \
      READ_A(qa0, qa1, qa2, qa3, 0, 6);                                       \
      READ_B1(qb, 1, 2);                                                      \
      BARRIER(); SCHEDB();                                                    \
      PRIO1; QUAD(2, pa0, pa1, pa2, pa3, PBSET); PRIO0; SCHEDB();             \
      if (S2) { WAITVM(4); } else { WAITVM(0); }                              \
      BARRIER();                                                              \
    }                                                                         \
    { /* p3: Q3(T). reads A01(T+1), B(T+1)ni3. stage A(T+2)h0. pub B(T+2) */  \
      READ_A(pa0, pa1, pa2, pa3, 1, 0);                                       \
      READ_B1(qb, 1, 3);                                                      \
      if (S2) STAGE_A(0, 0, (kt) + 128);                                      \
      BARRIER(); SCHEDB();                                                    \
      PRIO1; QUAD(3, qa0, qa1, qa2, qa3, PBSET); PRIO0; SCHEDB();             \
      if (S2) { WAITVM(2); }                                                  \
      BARRIER();                                                              \
    }                                                                         \
    { /* p4: Q0(T+1). reads A23(T+1), B(T+2)ni0. stage A(T+2)h1, B(T+3)h0 */  \
      READ_A(qa0, qa1, qa2, qa3, 1, 2);                                       \
      if (S2) READ_B1(pb, 0, 0);                                              \
      if (S2) STAGE_A(0, 1, (kt) + 128);                                      \
      if (S3) STAGE_B(1, 0, (kt) + 192);                                      \
      BARRIER(); SCHEDB();                                                    \
      PRIO1; QUAD(0, pa0, pa1, pa2, pa3, QBSET); PRIO0; SCHEDB();             \
      BARRIER();                                                              \
    }                                                                         \
    { /* p5: Q1(T+1). reads A45(T+1), B(T+2)ni1. stage B(T+3)h1 */            \
      READ_A(pa0, pa1, pa2, pa3, 1, 4);                                       \
      if (S2) READ_B1(pb, 0, 1);                                              \
      if (S3) STAGE_B(1, 1, (kt) + 192);                                      \
      BARRIER(); SCHEDB();                                                    \
      PRIO1; QUAD(1, qa0, qa1, qa2, qa3, QBSET); PRIO0; SCHEDB();             \
      BARRIER();                                                              \
    }                                                                         \
    { /* p6: Q2(T+1). reads A67(T+1), B(T+2)ni2. publish A(T+2) */            \
      READ_A(qa0, qa1, qa2, qa3, 1, 6);                                       \
      if (S2) READ_B1(pb, 0, 2);                                              \
      BARRIER(); SCHEDB();                                                    \
      PRIO1; QUAD(2, pa0, pa1, pa2, pa3, QBSET); PRIO0; SCHEDB();             \
      if (S2) { WAITVM(4); }                                                  \
      BARRIER();                                                              \
    }                                                                         \
    { /* p7: Q3(T+1). reads A01(T+2), B(T+2)ni3. stage A(T+3). pub B(T+3) */  \
      if (S2) READ_A(pa0, pa1, pa2, pa3, 0, 0);                               \
      if (S2) READ_B1(pb, 0, 3);                                              \
      if (S3) { STAGE_A(1, 0, (kt) + 192); STAGE_A(1, 1, (kt) + 192); }       \
      BARRIER(); SCHEDB();                                                    \
      PRIO1; QUAD(3, qa0, qa1, qa2, qa3, QBSET); PRIO0; SCHEDB();             \
      if (S3) { WAITVM(4); }                                                  \
      BARRIER();                                                              \
    }                                                                         \
  }

__global__ __launch_bounds__(512, 2) void gemm_kernel(
    const unsigned short* __restrict__ Abf,   // [8192][4096] bf16 (x)
    const unsigned short* __restrict__ Bbf,   // [4096][4096] bf16 (Weff)
    const float* __restrict__ bias,
    float* __restrict__ C) {
  const int K = D_IN, N = D_OUT;
  // 2 bufs x 256 rows x 64 k x bf16 = 64 KB per operand; 128 KB total
  __shared__ __align__(16) unsigned short sA[2 * 256 * 64];
  __shared__ __align__(16) unsigned short sB[2 * 256 * 64];
  const int t = threadIdx.x;
  const int lane = t & 63;
  const int wave = t >> 6;

  // XCD-bijective swizzle: 512 wgs, 8 XCDs, 64 wgs/XCD; consecutive swz
  // share bm (A panel, 2 MB, L2-resident per XCD).
  const int wgid = blockIdx.y * gridDim.x + blockIdx.x;     // 0..511
  const int swz = (wgid & 7) * 64 + (wgid >> 3);
  const int bn = swz & 15;                                  // 16 n-tiles
  const int bm = swz >> 4;                                  // 32 m-tiles

  const int wm = (wave >> 2) * 128;   // wave's A-row base within tile
  const int wn = (wave & 3) * 64;     // wave's B-row (C-col) base

  // staging: thread t covers rows (t>>3) + {0,64} of a half, chunk
  // (t&7)^(row&7) on the GLOBAL side (LDS dest pinned linear).
  const int tr = t >> 3;
  const int cg = (t & 7) ^ (tr & 7);
  const unsigned short* ag = Abf + (size_t)(bm * 256 + tr) * K + cg * 8;
  const unsigned short* bg = Bbf + (size_t)(bn * 256 + tr) * K + cg * 8;
  unsigned short* const lA = sA + t * 8;
  unsigned short* const lB = sB + t * 8;

  // fragment-read bases (undo swizzle at read time)
  const int lm = lane & 15;
  const int cb = lane >> 4;
  const int sw = lm & 7;
  const int ch0 = ((cb) ^ sw) * 8;        // ks=0 chunk element offset
  const int ch1 = ((4 + cb) ^ sw) * 8;    // ks=1
  const unsigned short* rA = sA + (wm + lm) * 64;
  const unsigned short* rB = sB + (wn + lm) * 64;

  f32x4 acc[8][4] = {};
  bf16x8 pa0, pa1, pa2, pa3;   // ping A-frag set
  bf16x8 qa0, qa1, qa2, qa3;   // pong A-frag set
  bf16x8 PBSET;                // ping B set (tile T, T+2, ...)
  bf16x8 QBSET;                // pong B set (tile T+1, T+3, ...)

  // prologue: stage tiles 0 and 1 fully; vmcnt(4) leaves A(tile1) in
  // flight (steady-state entry). Then fill pingB = B(tile0) and
  // pa = A01(tile0).
  STAGE_B(0, 0, 0); STAGE_B(0, 1, 0);
  STAGE_A(0, 0, 0); STAGE_A(0, 1, 0);
  STAGE_B(1, 0, 64); STAGE_B(1, 1, 64);
  STAGE_A(1, 0, 64); STAGE_A(1, 1, 64);
  WAITVM(4);
  BARRIER();
  READ_B1(pb, 0, 0); READ_B1(pb, 0, 1);
  READ_B1(pb, 0, 2); READ_B1(pb, 0, 3);
  READ_A(pa0, pa1, pa2, pa3, 0, 0);

#pragma unroll 1
  for (int kt = 0; kt < K - 128; kt += 128) GEMM_BODY(1, 1, kt)
  GEMM_BODY(0, 0, K - 128)   // tail: tiles 62,63, no prefetch beyond

  // epilogue: C/D layout col = lane&15, row = (lane>>4)*4 + reg
  const int cn = lane & 15;
  const int rm = (lane >> 4) * 4;
#pragma unroll
  for (int ni = 0; ni < 4; ++ni) {
    const int col = bn * 256 + wn + ni * 16 + cn;
    const float bv = bias[col];
#pragma unroll
    for (int mi = 0; mi < 8; ++mi) {
      const int row0 = bm * 256 + wm + mi * 16 + rm;
#pragma unroll
      for (int r = 0; r < 4; ++r)
        C[(size_t)(row0 + r) * N + col] = acc[mi][ni][r] + bv;
    }
  }
}

// ---------------------------------------------------------------------------
extern "C" void kernel_launch(void* const* d_in, const int* in_sizes, int n_in,
                              void* d_out, int out_size, void* d_ws, size_t ws_size,
                              hipStream_t stream) {
  const float* x    = (const float*)d_in[0];  // [8192,4096]
  const float* W    = (const float*)d_in[1];  // [4096,4096]
  const float* bias = (const float*)d_in[2];  // [4096]
  const float* As   = (const float*)d_in[3];  // [2,4096,64]
  const float* Bs   = (const float*)d_in[4];  // [2,64,64]
  const float* Cs   = (const float*)d_in[5];  // [2,64,4096] -> flat [128,4096]
  float* out = (float*)d_out;                 // [8192,4096] fp32

  char* ws = (char*)d_ws;
  float* ABt           = (float*)ws;                                       // 2 MB
  unsigned short* Weff = (unsigned short*)(ws + (2u << 20));               // 32 MB
  unsigned short* xb   = (unsigned short*)(ws + (2u << 20) + (32u << 20)); // 64 MB

  ab_kernel<<<2048, 256, 0, stream>>>(As, Bs, ABt);
  weff_kernel<<<dim3(64, 64), 256, 0, stream>>>(W, ABt, Cs, Weff);
  cast_kernel<<<16384, 256, 0, stream>>>(x, xb);
  gemm_kernel<<<dim3(16, 32), 512, 0, stream>>>(xb, Weff, bias, out);
}

// Round 4
// 556.512 us; speedup vs baseline: 1.1208x; 1.1208x over previous
//
#include <hip/hip_runtime.h>
#include <hip/hip_bf16.h>

typedef __bf16 bf16x8 __attribute__((ext_vector_type(8)));
typedef float f32x4 __attribute__((ext_vector_type(4)));

#define TOKENS 8192
#define D_IN   4096
#define D_OUT  4096

// fp32 -> bf16 bits, round-to-nearest-even
static __device__ __forceinline__ unsigned short f2bf(float f) {
  union { float f; unsigned int u; } v; v.f = f;
  unsigned int r = v.u + 0x7FFFu + ((v.u >> 16) & 1u);
  return (unsigned short)(r >> 16);
}

// ---------------------------------------------------------------------------
// Kernel 1: ABt_bf16[o][f*64+k] = bf16( sum_r tanh(As[f,o,r]) * Bs[f,r,k] )
// ---------------------------------------------------------------------------
__global__ void ab_kernel(const float* __restrict__ As,
                          const float* __restrict__ Bs,
                          unsigned short* __restrict__ ABt) {
  __shared__ float tA[4][64];
  __shared__ float sB[64][64];
  const int t = threadIdx.x;
  const int f = blockIdx.x >> 10;
  const int o0 = (blockIdx.x & 1023) * 4;
  const int ol = t >> 6;
  const int k  = t & 63;
  tA[ol][k] = tanhf(As[((size_t)f * 4096 + o0 + ol) * 64 + k]);
#pragma unroll
  for (int j = 0; j < 16; ++j) {
    int e = t + 256 * j;
    sB[e >> 6][e & 63] = Bs[f * 4096 + e];
  }
  __syncthreads();
  float acc = 0.f;
#pragma unroll
  for (int r = 0; r < 64; ++r) acc += tA[ol][r] * sB[r][k];
  ABt[(size_t)(o0 + ol) * 128 + f * 64 + k] = f2bf(acc);
}

// ---------------------------------------------------------------------------
// Kernel 3 (launched 2nd): cast x fp32->bf16 (blocks < 16384), plus
// transpose-cast Cs [128][4096] fp32 -> Cst [4096][128] bf16 (128 blocks).
// Transpose via padded-LDS 64x64 tile: all global reads/writes coalesced,
// LDS banks conflict-free (pad 65).
// ---------------------------------------------------------------------------
__global__ void cast_kernel(const float* __restrict__ x,
                            unsigned short* __restrict__ xb,
                            const float* __restrict__ Cs,
                            unsigned short* __restrict__ Cst) {
  __shared__ float tp[64][65];
  const int t = threadIdx.x;
  if (blockIdx.x < 16384) {
    size_t i = ((size_t)blockIdx.x * 256 + t) * 8;
    float4 a = *(const float4*)(x + i);
    float4 b = *(const float4*)(x + i + 4);
    union { unsigned short h[8]; uint4 u; } p;
    p.h[0] = f2bf(a.x); p.h[1] = f2bf(a.y);
    p.h[2] = f2bf(a.z); p.h[3] = f2bf(a.w);
    p.h[4] = f2bf(b.x); p.h[5] = f2bf(b.y);
    p.h[6] = f2bf(b.z); p.h[7] = f2bf(b.w);
    *(uint4*)(xb + i) = p.u;
  } else {
    const int b2 = blockIdx.x - 16384;      // 0..127
    const int k0 = (b2 & 1) * 64;
    const int i0 = (b2 >> 1) * 64;
#pragma unroll
    for (int j = 0; j < 16; ++j) {
      int e = t + 256 * j;                  // kl = e>>6, il = e&63
      tp[e >> 6][e & 63] = Cs[(size_t)(k0 + (e >> 6)) * 4096 + i0 + (e & 63)];
    }
    __syncthreads();
#pragma unroll
    for (int j = 0; j < 16; ++j) {
      int e = t + 256 * j;                  // il = e>>6, kl = e&63
      Cst[(size_t)(i0 + (e >> 6)) * 128 + k0 + (e & 63)] =
          f2bf(tp[e & 63][e >> 6]);
    }
  }
}

// ---------------------------------------------------------------------------
// Kernel 2 (launched 3rd): Weff[o][i] = bf16( W[o][i] + ABt · Cst^T ) via
// MFMA. M=o, N=i, K=128; both operands K-contiguous bf16. 128x128 tile,
// 4 waves, 2 K-steps of 64, m97-style swizzled global_load_lds staging
// (zero bank conflicts, proven in the main gemm). Replaces the scalar-LDS
// fp32 weff (~120-200us LDS-pipe bound) with ~25-35us memory-floor work.
// ---------------------------------------------------------------------------
__global__ __launch_bounds__(256) void weff_kernel(
    const float* __restrict__ W,
    const unsigned short* __restrict__ ABt,   // [4096][128] bf16
    const unsigned short* __restrict__ Cst,   // [4096][128] bf16
    unsigned short* __restrict__ Weff) {
  const int KW = 128;
  __shared__ __align__(16) unsigned short sA[128 * 64];  // 16 KB
  __shared__ __align__(16) unsigned short sB[128 * 64];  // 16 KB
  const int t = threadIdx.x;
  const int lane = t & 63;
  const int wave = t >> 6;
  const int bi = blockIdx.x, bo = blockIdx.y;
  const int wm = (wave & 1) * 64, wn = (wave >> 1) * 64;

  const int tr = t >> 3;                    // 0..31
  const int cg = (t & 7) ^ (tr & 7);        // swizzled global chunk
  const unsigned short* agA = ABt + (size_t)(bo * 128 + tr) * KW + cg * 8;
  const unsigned short* agB = Cst + (size_t)(bi * 128 + tr) * KW + cg * 8;
  unsigned short* const la = sA + t * 8;
  unsigned short* const lb = sB + t * 8;

  f32x4 acc[4][4] = {};
  const int lm = lane & 15;
  const int cb = lane >> 4;
  const int sw = lm & 7;

  for (int kt = 0; kt < KW; kt += 64) {
    __syncthreads();
#pragma unroll
    for (int j = 0; j < 4; ++j) {
      __builtin_amdgcn_global_load_lds(
          (const __attribute__((address_space(1))) void*)(agA + (size_t)j * 32 * KW + kt),
          (__attribute__((address_space(3))) void*)(la + j * 2048), 16, 0, 0);
      __builtin_amdgcn_global_load_lds(
          (const __attribute__((address_space(1))) void*)(agB + (size_t)j * 32 * KW + kt),
          (__attribute__((address_space(3))) void*)(lb + j * 2048), 16, 0, 0);
    }
    __syncthreads();
#pragma unroll
    for (int ks = 0; ks < 2; ++ks) {
      const int ch = ((ks * 4 + cb) ^ sw) * 8;
      bf16x8 af[4], bfr[4];
#pragma unroll
      for (int mi = 0; mi < 4; ++mi)
        af[mi] = *(const bf16x8*)(sA + (wm + mi * 16 + lm) * 64 + ch);
#pragma unroll
      for (int ni = 0; ni < 4; ++ni)
        bfr[ni] = *(const bf16x8*)(sB + (wn + ni * 16 + lm) * 64 + ch);
#pragma unroll
      for (int mi = 0; mi < 4; ++mi)
#pragma unroll
        for (int ni = 0; ni < 4; ++ni)
          acc[mi][ni] = __builtin_amdgcn_mfma_f32_16x16x32_bf16(
              af[mi], bfr[ni], acc[mi][ni], 0, 0, 0);
    }
  }

  // epilogue: D layout col = lane&15, row = (lane>>4)*4 + r. Add W, cast.
  const int cn = lane & 15;
  const int rm = (lane >> 4) * 4;
#pragma unroll
  for (int ni = 0; ni < 4; ++ni) {
    const int col = bi * 128 + wn + ni * 16 + cn;
#pragma unroll
    for (int mi = 0; mi < 4; ++mi) {
      const int row0 = bo * 128 + wm + mi * 16 + rm;
#pragma unroll
      for (int r = 0; r < 4; ++r) {
        const int row = row0 + r;
        Weff[(size_t)row * D_IN + col] =
            f2bf(W[(size_t)row * D_IN + col] + acc[mi][ni][r]);
      }
    }
  }
}

// ---------------------------------------------------------------------------
// Kernel 4: main GEMM  C[m][n] = sum_k A[m][k]*B[n][k] + bias[n]
// R2 schedule (best measured: 273.8us, MfmaUtil 43.7, 0 bank conflicts):
// 256x256 tile, BK=64, 8 waves, 8-phase counted-vmcnt, A-frag ping/pong
// prefetch, B-frags read in-phase at p0/p4, publishes at p2/p6.
// ---------------------------------------------------------------------------

#define FENCE()   asm volatile("" ::: "memory")
#define BARRIER() do { FENCE(); __builtin_amdgcn_s_barrier(); FENCE(); } while (0)
#define WAITVM(n)  asm volatile("s_waitcnt vmcnt(" #n ")" ::: "memory")
#define SCHEDB()   __builtin_amdgcn_sched_barrier(0)
#define PRIO1      __builtin_amdgcn_s_setprio(1)
#define PRIO0      __builtin_amdgcn_s_setprio(0)

#define GLOAD(gptr, lptr)                                                     \
  __builtin_amdgcn_global_load_lds(                                           \
      (const __attribute__((address_space(1))) void*)(gptr),                  \
      (__attribute__((address_space(3))) void*)(lptr), 16, 0, 0)

// one operand-half = 128 rows x 64 k = 16 KB = 2 loads/thread (512 thr x 16B)
#define STAGE_A(buf, h, kt) do {                                              \
    GLOAD(ag + (size_t)((h) * 128) * K + (kt),                                \
          lA + (buf) * 16384 + (h) * 8192);                                   \
    GLOAD(ag + (size_t)((h) * 128 + 64) * K + (kt),                           \
          lA + (buf) * 16384 + (h) * 8192 + 4096);                            \
  } while (0)
#define STAGE_B(buf, h, kt) do {                                              \
    GLOAD(bg + (size_t)((h) * 128) * K + (kt),                                \
          lB + (buf) * 16384 + (h) * 8192);                                   \
    GLOAD(bg + (size_t)((h) * 128 + 64) * K + (kt),                           \
          lB + (buf) * 16384 + (h) * 8192 + 4096);                            \
  } while (0)

#define LDA(buf, mi, ks) \
  (*(const bf16x8*)(rA + (buf) * 16384 + (mi) * 1024 + ((ks) ? ch1 : ch0)))
#define LDB(buf, ni, ks) \
  (*(const bf16x8*)(rB + (buf) * 16384 + (ni) * 1024 + ((ks) ? ch1 : ch0)))

// R0 = mi-even ks0, R1 = mi-even ks1, R2 = mi-odd ks0, R3 = mi-odd ks1.
#define READ_A(R0, R1, R2, R3, buf, mi0) do {                                 \
    R0 = LDA(buf, (mi0), 0);                                                  \
    R2 = LDA(buf, (mi0) + 1, 0);                                              \
    R1 = LDA(buf, (mi0), 1);                                                  \
    R3 = LDA(buf, (mi0) + 1, 1);                                              \
  } while (0)
#define READ_B(buf) do {                                                      \
    b00 = LDB(buf, 0, 0); b10 = LDB(buf, 1, 0);                               \
    b20 = LDB(buf, 2, 0); b30 = LDB(buf, 3, 0);                               \
    b01 = LDB(buf, 0, 1); b11 = LDB(buf, 1, 1);                               \
    b21 = LDB(buf, 2, 1); b31 = LDB(buf, 3, 1);                               \
  } while (0)

#define MFMA1(d, a, b) \
  (d) = __builtin_amdgcn_mfma_f32_16x16x32_bf16((a), (b), (d), 0, 0, 0)

// 16 MFMAs: mi {2q,2q+1} x ni 0..3 x ks 0..1 (ks0 half first)
#define QUAD(q, A0, A1, A2, A3)                                               \
    MFMA1(acc[2*(q)  ][0], A0, b00);                                          \
    MFMA1(acc[2*(q)+1][0], A2, b00);                                          \
    MFMA1(acc[2*(q)  ][1], A0, b10);                                          \
    MFMA1(acc[2*(q)+1][1], A2, b10);                                          \
    MFMA1(acc[2*(q)  ][2], A0, b20);                                          \
    MFMA1(acc[2*(q)+1][2], A2, b20);                                          \
    MFMA1(acc[2*(q)  ][3], A0, b30);                                          \
    MFMA1(acc[2*(q)+1][3], A2, b30);                                          \
    MFMA1(acc[2*(q)  ][0], A1, b01);                                          \
    MFMA1(acc[2*(q)+1][0], A3, b01);                                          \
    MFMA1(acc[2*(q)  ][1], A1, b11);                                          \
    MFMA1(acc[2*(q)+1][1], A3, b11);                                          \
    MFMA1(acc[2*(q)  ][2], A1, b21);                                          \
    MFMA1(acc[2*(q)+1][2], A3, b21);                                          \
    MFMA1(acc[2*(q)  ][3], A1, b31);                                          \
    MFMA1(acc[2*(q)+1][3], A3, b31);

#define GEMM_BODY(S2, S3, kt)                                                 \
  {                                                                           \
    /* p0: B(T) + A23(T) reads; stage A(T+1) h0+h1 */                         \
    READ_B(0);                                                                \
    READ_A(qa0, qa1, qa2, qa3, 0, 2);                                         \
    STAGE_A(1, 0, (kt) + 64); STAGE_A(1, 1, (kt) + 64);                       \
    BARRIER(); SCHEDB();                                                      \
    PRIO1; QUAD(0, pa0, pa1, pa2, pa3); PRIO0; SCHEDB();                      \
    BARRIER();                                                                \
    /* p1: A45(T); stage B(T+2) h0+h1 */                                      \
    READ_A(pa0, pa1, pa2, pa3, 0, 4);                                         \
    if (S2) { STAGE_B(0, 0, (kt) + 128); STAGE_B(0, 1, (kt) + 128); }         \
    BARRIER(); SCHEDB();                                                      \
    PRIO1; QUAD(1, qa0, qa1, qa2, qa3); PRIO0; SCHEDB();                      \
    BARRIER();                                                                \
    /* p2: A67(T); vm-publish buf1 (T+1 data complete) */                     \
    READ_A(qa0, qa1, qa2, qa3, 0, 6);                                         \
    BARRIER(); SCHEDB();                                                      \
    PRIO1; QUAD(2, pa0, pa1, pa2, pa3); PRIO0; SCHEDB();                      \
    if (S2) { WAITVM(4); } else { WAITVM(0); }                                \
    BARRIER();                                                                \
    /* p3: A01(T+1) prefetch (buf1 published) */                              \
    READ_A(pa0, pa1, pa2, pa3, 1, 0);                                         \
    BARRIER(); SCHEDB();                                                      \
    PRIO1; QUAD(3, qa0, qa1, qa2, qa3); PRIO0; SCHEDB();                      \
    BARRIER();                                                                \
    /* p4: B(T+1) + A23(T+1); stage A(T+2) h0+h1 */                           \
    READ_B(1);                                                                \
    READ_A(qa0, qa1, qa2, qa3, 1, 2);                                         \
    if (S2) { STAGE_A(0, 0, (kt) + 128); STAGE_A(0, 1, (kt) + 128); }         \
    BARRIER(); SCHEDB();                                                      \
    PRIO1; QUAD(0, pa0, pa1, pa2, pa3); PRIO0; SCHEDB();                      \
    BARRIER();                                                                \
    /* p5: A45(T+1); stage B(T+3) h0+h1 */                                    \
    READ_A(pa0, pa1, pa2, pa3, 1, 4);                                         \
    if (S3) { STAGE_B(1, 0, (kt) + 192); STAGE_B(1, 1, (kt) + 192); }         \
    BARRIER(); SCHEDB();                                                      \
    PRIO1; QUAD(1, qa0, qa1, qa2, qa3); PRIO0; SCHEDB();                      \
    BARRIER();                                                                \
    /* p6: A67(T+1); vm-publish buf0 (T+2 data complete) */                   \
    READ_A(qa0, qa1, qa2, qa3, 1, 6);                                         \
    BARRIER(); SCHEDB();                                                      \
    PRIO1; QUAD(2, pa0, pa1, pa2, pa3); PRIO0; SCHEDB();                      \
    if (S3) { WAITVM(4); } else { WAITVM(0); }                                \
    BARRIER();                                                                \
    /* p7: A01(T+2) prefetch (buf0 published) */                              \
    if (S2) { READ_A(pa0, pa1, pa2, pa3, 0, 0); }                             \
    BARRIER(); SCHEDB();                                                      \
    PRIO1; QUAD(3, qa0, qa1, qa2, qa3); PRIO0; SCHEDB();                      \
    BARRIER();                                                                \
  }

__global__ __launch_bounds__(512, 2) void gemm_kernel(
    const unsigned short* __restrict__ Abf,   // [8192][4096] bf16 (x)
    const unsigned short* __restrict__ Bbf,   // [4096][4096] bf16 (Weff)
    const float* __restrict__ bias,
    float* __restrict__ C) {
  const int K = D_IN, N = D_OUT;
  __shared__ __align__(16) unsigned short sA[2 * 256 * 64];
  __shared__ __align__(16) unsigned short sB[2 * 256 * 64];
  const int t = threadIdx.x;
  const int lane = t & 63;
  const int wave = t >> 6;

  const int wgid = blockIdx.y * gridDim.x + blockIdx.x;     // 0..511
  const int swz = (wgid & 7) * 64 + (wgid >> 3);
  const int bn = swz & 15;                                  // 16 n-tiles
  const int bm = swz >> 4;                                  // 32 m-tiles

  const int wm = (wave >> 2) * 128;
  const int wn = (wave & 3) * 64;

  const int tr = t >> 3;
  const int cg = (t & 7) ^ (tr & 7);
  const unsigned short* ag = Abf + (size_t)(bm * 256 + tr) * K + cg * 8;
  const unsigned short* bg = Bbf + (size_t)(bn * 256 + tr) * K + cg * 8;
  unsigned short* const lA = sA + t * 8;
  unsigned short* const lB = sB + t * 8;

  const int lm = lane & 15;
  const int cb = lane >> 4;
  const int sw = lm & 7;
  const int ch0 = ((cb) ^ sw) * 8;
  const int ch1 = ((4 + cb) ^ sw) * 8;
  const unsigned short* rA = sA + (wm + lm) * 64;
  const unsigned short* rB = sB + (wn + lm) * 64;

  f32x4 acc[8][4] = {};
  bf16x8 pa0, pa1, pa2, pa3;   // ping A-frag set
  bf16x8 qa0, qa1, qa2, qa3;   // pong A-frag set
  bf16x8 b00, b10, b20, b30, b01, b11, b21, b31;

  STAGE_B(0, 0, 0); STAGE_B(0, 1, 0);
  STAGE_A(0, 0, 0); STAGE_A(0, 1, 0);
  STAGE_B(1, 0, 64); STAGE_B(1, 1, 64);
  WAITVM(4);
  BARRIER();
  READ_A(pa0, pa1, pa2, pa3, 0, 0);

#pragma unroll 1
  for (int kt = 0; kt < K - 128; kt += 128) GEMM_BODY(1, 1, kt)
  GEMM_BODY(0, 0, K - 128)   // tail: tiles 62,63, no prefetch beyond

  const int cn = lane & 15;
  const int rm = (lane >> 4) * 4;
#pragma unroll
  for (int ni = 0; ni < 4; ++ni) {
    const int col = bn * 256 + wn + ni * 16 + cn;
    const float bv = bias[col];
#pragma unroll
    for (int mi = 0; mi < 8; ++mi) {
      const int row0 = bm * 256 + wm + mi * 16 + rm;
#pragma unroll
      for (int r = 0; r < 4; ++r)
        C[(size_t)(row0 + r) * N + col] = acc[mi][ni][r] + bv;
    }
  }
}

// ---------------------------------------------------------------------------
extern "C" void kernel_launch(void* const* d_in, const int* in_sizes, int n_in,
                              void* d_out, int out_size, void* d_ws, size_t ws_size,
                              hipStream_t stream) {
  const float* x    = (const float*)d_in[0];  // [8192,4096]
  const float* W    = (const float*)d_in[1];  // [4096,4096]
  const float* bias = (const float*)d_in[2];  // [4096]
  const float* As   = (const float*)d_in[3];  // [2,4096,64]
  const float* Bs   = (const float*)d_in[4];  // [2,64,64]
  const float* Cs   = (const float*)d_in[5];  // [2,64,4096] -> flat [128,4096]
  float* out = (float*)d_out;                 // [8192,4096] fp32

  char* ws = (char*)d_ws;
  unsigned short* ABt  = (unsigned short*)ws;                               // 1 MB
  unsigned short* Cst  = (unsigned short*)(ws + (1u << 20));                // 1 MB
  unsigned short* Weff = (unsigned short*)(ws + (2u << 20));                // 32 MB
  unsigned short* xb   = (unsigned short*)(ws + (2u << 20) + (32u << 20));  // 64 MB

  ab_kernel<<<2048, 256, 0, stream>>>(As, Bs, ABt);
  cast_kernel<<<16384 + 128, 256, 0, stream>>>(x, xb, Cs, Cst);
  weff_kernel<<<dim3(32, 32), 256, 0, stream>>>(W, ABt, Cst, Weff);
  gemm_kernel<<<dim3(16, 32), 512, 0, stream>>>(xb, Weff, bias, out);
}